// Round 2
// baseline (278.614 us; speedup 1.0000x reference)
//
#include <hip/hip_runtime.h>

// ProST projective spatial transformer forward:
// out[b,0,h,w] = sum_k trilinear(vol[b], M_b * (s + t_k * dir(h,w)))
// B=2, C=1, vol 256^3, detector 256x256, K=128.
//
// Mapping: block = 256 threads = 64 (w-lane) x 4 (K-quarter); each thread
// integrates 32 samples; 4 partials per pixel reduced through LDS.
// Grid = B*H*(W/64) = 2048 blocks.

#define VOL_N      256
#define K_SAMP     128
#define K_SPLIT    4
#define K_PER      (K_SAMP / K_SPLIT)   // 32

__global__ __launch_bounds__(256) void prost_fwd(
    const float* __restrict__ vol,     // [B,1,256,256,256]
    const float* __restrict__ Tm,      // [B,3,4]
    const float* __restrict__ corner,  // [B,8,4]
    const float* __restrict__ param,   // [src, det, pix_spacing, step_size]
    float* __restrict__ out)           // [B,1,256,256]
{
    const int tid  = threadIdx.x;
    const int wl   = tid & 63;          // lane within w-group
    const int kq   = tid >> 6;          // which K-quarter
    const int bid  = blockIdx.x;
    const int wblk = bid & 3;           // W/64 = 4 groups
    const int h    = (bid >> 2) & 255;
    const int b    = bid >> 10;         // batch

    const float src = param[0];
    const float det = param[1];
    const float pix = param[2];

    // ---- transform matrix (uniform per block -> scalar loads) ----
    const float* M = Tm + b * 12;
    const float m00 = M[0], m01 = M[1],  m02 = M[2],  m03 = M[3];
    const float m10 = M[4], m11 = M[5],  m12 = M[6],  m13 = M[7];
    const float m20 = M[8], m21 = M[9],  m22 = M[10], m23 = M[11];

    // ---- ray-distance range from the 8 transformed corners ----
    const float* cp = corner + b * 32;
    float dmin =  1e30f, dmax = -1e30f;
    #pragma unroll
    for (int c = 0; c < 8; ++c) {
        const float cx = cp[c * 4 + 0], cy = cp[c * 4 + 1];
        const float cz = cp[c * 4 + 2], cw = cp[c * 4 + 3];
        const float q0 = m00 * cx + m01 * cy + m02 * cz + m03 * cw;
        const float q1 = m10 * cx + m11 * cy + m12 * cz + m13 * cw;
        const float q2 = m20 * cx + m21 * cy + m22 * cz + m23 * cw - src;
        const float d  = sqrtf(q0 * q0 + q1 * q1 + q2 * q2);
        dmin = fminf(dmin, d);
        dmax = fmaxf(dmax, d);
    }

    // ---- per-pixel ray direction (normalized) ----
    const int   w  = wblk * 64 + wl;
    const float wx = ((float)w - 127.5f) * pix;
    const float hy = ((float)h - 127.5f) * pix;
    // dirs = (wx, hy, (src-det)) - (0,0,src) = (wx, hy, -det), then normalize
    const float inv_n = 1.0f / sqrtf(wx * wx + hy * hy + det * det);
    const float dirx = wx * inv_n;
    const float diry = hy * inv_n;
    const float dirz = -det * inv_n;

    // ---- fold affine chain: voxel_coord_i(t) = ca_i + t * cb_i ----
    // p(t) = (t*dirx, t*diry, src + t*dirz); q_i = M_i . (p,1)
    const float bd0 = m00 * dirx + m01 * diry + m02 * dirz;
    const float bd1 = m10 * dirx + m11 * diry + m12 * dirz;
    const float bd2 = m20 * dirx + m21 * diry + m22 * dirz;
    const float a0  = m02 * src + m03;
    const float a1  = m12 * src + m13;
    const float a2  = m22 * src + m23;
    // grid -> voxel: g = (q + 1) * 127.5
    const float ca0 = (a0 + 1.0f) * 127.5f, cb0 = bd0 * 127.5f;
    const float ca1 = (a1 + 1.0f) * 127.5f, cb1 = bd1 * 127.5f;
    const float ca2 = (a2 + 1.0f) * 127.5f, cb2 = bd2 * 127.5f;

    // t_k = dmin + dspan * k/(K-1)  ->  voxel(k) = p0 + k * s
    const float dspan = dmax - dmin;
    const float tstep = dspan * (1.0f / (float)(K_SAMP - 1));
    const float p0x = fmaf(dmin, cb0, ca0), sx = tstep * cb0;
    const float p0y = fmaf(dmin, cb1, ca1), sy = tstep * cb1;
    const float p0z = fmaf(dmin, cb2, ca2), sz = tstep * cb2;

    const float* __restrict__ volb =
        vol + (size_t)b * (VOL_N * VOL_N * VOL_N);

    float acc = 0.0f;
    float fk  = (float)(kq * K_PER);
    #pragma unroll 4
    for (int k = 0; k < K_PER; ++k, fk += 1.0f) {
        const float fx = fmaf(fk, sx, p0x);
        const float fy = fmaf(fk, sy, p0y);
        const float fz = fmaf(fk, sz, p0z);
        const float x0f = floorf(fx), y0f = floorf(fy), z0f = floorf(fz);
        const float xd = fx - x0f, yd = fy - y0f, zd = fz - z0f;
        int ix0 = (int)x0f, iy0 = (int)y0f, iz0 = (int)z0f;
        int ix1 = ix0 + 1,  iy1 = iy0 + 1,  iz1 = iz0 + 1;
        ix0 = min(max(ix0, 0), 255); ix1 = min(max(ix1, 0), 255);
        iy0 = min(max(iy0, 0), 255); iy1 = min(max(iy1, 0), 255);
        iz0 = min(max(iz0, 0), 255); iz1 = min(max(iz1, 0), 255);
        const int yo0 = iy0 << 8,  yo1 = iy1 << 8;
        const int zo0 = iz0 << 16, zo1 = iz1 << 16;

        const float v000 = volb[zo0 + yo0 + ix0];
        const float v001 = volb[zo0 + yo0 + ix1];
        const float v010 = volb[zo0 + yo1 + ix0];
        const float v011 = volb[zo0 + yo1 + ix1];
        const float v100 = volb[zo1 + yo0 + ix0];
        const float v101 = volb[zo1 + yo0 + ix1];
        const float v110 = volb[zo1 + yo1 + ix0];
        const float v111 = volb[zo1 + yo1 + ix1];

        const float c00 = fmaf(xd, v001 - v000, v000);
        const float c01 = fmaf(xd, v011 - v010, v010);
        const float c10 = fmaf(xd, v101 - v100, v100);
        const float c11 = fmaf(xd, v111 - v110, v110);
        const float c0  = fmaf(yd, c01 - c00, c00);
        const float c1  = fmaf(yd, c11 - c10, c10);
        acc += fmaf(zd, c1 - c0, c0);
    }

    // ---- reduce the 4 K-quarters per pixel through LDS ----
    __shared__ float part[256];
    part[tid] = acc;
    __syncthreads();
    if (kq == 0) {
        const float s = part[wl] + part[wl + 64] + part[wl + 128] + part[wl + 192];
        // out[b,0,h,w]
        out[(((b * 256) + h) << 8) + w] = s;
    }
}

extern "C" void kernel_launch(void* const* d_in, const int* in_sizes, int n_in,
                              void* d_out, int out_size, void* d_ws, size_t ws_size,
                              hipStream_t stream) {
    const float* x      = (const float*)d_in[0];  // [2,1,256,256,256]
    // d_in[1] = y, only its shape matters (256x256) -> unused
    const float* Tm     = (const float*)d_in[2];  // [2,3,4]
    const float* corner = (const float*)d_in[3];  // [2,8,4]
    const float* param  = (const float*)d_in[4];  // [4]
    // d_in[5] = K (=128), hardcoded
    float* out = (float*)d_out;                   // [2,1,256,256]

    const int blocks = 2 * 256 * (256 / 64);      // 2048
    prost_fwd<<<blocks, 256, 0, stream>>>(x, Tm, corner, param, out);
}

// Round 10
// 276.728 us; speedup vs baseline: 1.0068x; 1.0068x over previous
//
#include <hip/hip_runtime.h>

// ProST projective spatial transformer forward:
// out[b,0,h,w] = sum_k trilinear(vol[b], M_b * (s + t_k * dir(h,w)))
// B=2, C=1, vol 256^3, detector 256x256, K=128.
//
// R2 finding: VGPR=20, VALUBusy=21%, HBM 16% -> gather-latency-bound with
// zero MLP (compiler recycled regs, vmcnt(0) per cluster).
// R3 change: explicit 2-deep software pipeline (named buffers A/B).
// R6 hardening: __builtin_amdgcn_sched_barrier(0) after each issue phase so
// the scheduler CANNOT sink the gathers back into the consume phase -> at
// every lerp, the other buffer's 8 loads are in flight (vmcnt(8) waits).

#define VOL_N      256
#define K_SAMP     128
#define K_SPLIT    4
#define K_PER      (K_SAMP / K_SPLIT)   // 32

struct Samp {
    float v000, v001, v010, v011, v100, v101, v110, v111;
    float xd, yd, zd;
};

__device__ __forceinline__ void samp_issue(
    const float* __restrict__ volb, float fk,
    float sx, float sy, float sz,
    float p0x, float p0y, float p0z, Samp& S)
{
    const float fx = fmaf(fk, sx, p0x);
    const float fy = fmaf(fk, sy, p0y);
    const float fz = fmaf(fk, sz, p0z);
    const float x0f = floorf(fx), y0f = floorf(fy), z0f = floorf(fz);
    S.xd = fx - x0f; S.yd = fy - y0f; S.zd = fz - z0f;
    int ix0 = (int)x0f, iy0 = (int)y0f, iz0 = (int)z0f;
    int ix1 = ix0 + 1,  iy1 = iy0 + 1,  iz1 = iz0 + 1;
    ix0 = min(max(ix0, 0), 255); ix1 = min(max(ix1, 0), 255);
    iy0 = min(max(iy0, 0), 255); iy1 = min(max(iy1, 0), 255);
    iz0 = min(max(iz0, 0), 255); iz1 = min(max(iz1, 0), 255);
    const int a00 = (iz0 << 16) + (iy0 << 8);
    const int a01 = (iz0 << 16) + (iy1 << 8);
    const int a10 = (iz1 << 16) + (iy0 << 8);
    const int a11 = (iz1 << 16) + (iy1 << 8);
    S.v000 = volb[a00 + ix0];
    S.v001 = volb[a00 + ix1];
    S.v010 = volb[a01 + ix0];
    S.v011 = volb[a01 + ix1];
    S.v100 = volb[a10 + ix0];
    S.v101 = volb[a10 + ix1];
    S.v110 = volb[a11 + ix0];
    S.v111 = volb[a11 + ix1];
}

__device__ __forceinline__ float samp_lerp(const Samp& S)
{
    const float c00 = fmaf(S.xd, S.v001 - S.v000, S.v000);
    const float c01 = fmaf(S.xd, S.v011 - S.v010, S.v010);
    const float c10 = fmaf(S.xd, S.v101 - S.v100, S.v100);
    const float c11 = fmaf(S.xd, S.v111 - S.v110, S.v110);
    const float c0  = fmaf(S.yd, c01 - c00, c00);
    const float c1  = fmaf(S.yd, c11 - c10, c10);
    return fmaf(S.zd, c1 - c0, c0);
}

__global__ __launch_bounds__(256) void prost_fwd(
    const float* __restrict__ vol,     // [B,1,256,256,256]
    const float* __restrict__ Tm,      // [B,3,4]
    const float* __restrict__ corner,  // [B,8,4]
    const float* __restrict__ param,   // [src, det, pix_spacing, step_size]
    float* __restrict__ out)           // [B,1,256,256]
{
    const int tid  = threadIdx.x;
    const int wl   = tid & 63;          // lane within w-group
    const int kq   = tid >> 6;          // which K-quarter
    const int bid  = blockIdx.x;
    const int wblk = bid & 3;           // W/64 = 4 groups
    const int h    = (bid >> 2) & 255;
    const int b    = bid >> 10;         // batch

    const float src = param[0];
    const float det = param[1];
    const float pix = param[2];

    // ---- transform matrix (uniform per block -> scalar loads) ----
    const float* M = Tm + b * 12;
    const float m00 = M[0], m01 = M[1],  m02 = M[2],  m03 = M[3];
    const float m10 = M[4], m11 = M[5],  m12 = M[6],  m13 = M[7];
    const float m20 = M[8], m21 = M[9],  m22 = M[10], m23 = M[11];

    // ---- ray-distance range from the 8 transformed corners ----
    const float* cp = corner + b * 32;
    float dmin =  1e30f, dmax = -1e30f;
    #pragma unroll
    for (int c = 0; c < 8; ++c) {
        const float cx = cp[c * 4 + 0], cy = cp[c * 4 + 1];
        const float cz = cp[c * 4 + 2], cw = cp[c * 4 + 3];
        const float q0 = m00 * cx + m01 * cy + m02 * cz + m03 * cw;
        const float q1 = m10 * cx + m11 * cy + m12 * cz + m13 * cw;
        const float q2 = m20 * cx + m21 * cy + m22 * cz + m23 * cw - src;
        const float d  = sqrtf(q0 * q0 + q1 * q1 + q2 * q2);
        dmin = fminf(dmin, d);
        dmax = fmaxf(dmax, d);
    }

    // ---- per-pixel ray direction (normalized) ----
    const int   w  = wblk * 64 + wl;
    const float wx = ((float)w - 127.5f) * pix;
    const float hy = ((float)h - 127.5f) * pix;
    const float inv_n = 1.0f / sqrtf(wx * wx + hy * hy + det * det);
    const float dirx = wx * inv_n;
    const float diry = hy * inv_n;
    const float dirz = -det * inv_n;

    // ---- fold affine chain: voxel_coord_i(t) = ca_i + t * cb_i ----
    const float bd0 = m00 * dirx + m01 * diry + m02 * dirz;
    const float bd1 = m10 * dirx + m11 * diry + m12 * dirz;
    const float bd2 = m20 * dirx + m21 * diry + m22 * dirz;
    const float a0  = m02 * src + m03;
    const float a1  = m12 * src + m13;
    const float a2  = m22 * src + m23;
    const float ca0 = (a0 + 1.0f) * 127.5f, cb0 = bd0 * 127.5f;
    const float ca1 = (a1 + 1.0f) * 127.5f, cb1 = bd1 * 127.5f;
    const float ca2 = (a2 + 1.0f) * 127.5f, cb2 = bd2 * 127.5f;

    // t_k = dmin + dspan * k/(K-1)  ->  voxel(k) = p0 + k * s
    const float dspan = dmax - dmin;
    const float tstep = dspan * (1.0f / (float)(K_SAMP - 1));
    const float p0x = fmaf(dmin, cb0, ca0), sx = tstep * cb0;
    const float p0y = fmaf(dmin, cb1, ca1), sy = tstep * cb1;
    const float p0z = fmaf(dmin, cb2, ca2), sz = tstep * cb2;

    const float* __restrict__ volb =
        vol + (size_t)b * (VOL_N * VOL_N * VOL_N);

    // ---- K-march, 2-deep software pipeline, scheduler-pinned ----
    float acc = 0.0f;
    const float fk0 = (float)(kq * K_PER);
    Samp A, B;
    samp_issue(volb, fk0 + 0.0f, sx, sy, sz, p0x, p0y, p0z, A);
    samp_issue(volb, fk0 + 1.0f, sx, sy, sz, p0x, p0y, p0z, B);
    __builtin_amdgcn_sched_barrier(0);   // loads above stay above
    #pragma unroll 3
    for (int k = 2; k < K_PER; k += 2) {
        acc += samp_lerp(A);   // waits A only; B's 8 loads in flight
        samp_issue(volb, fk0 + (float)k, sx, sy, sz, p0x, p0y, p0z, A);
        __builtin_amdgcn_sched_barrier(0);   // A(next) cannot sink below
        acc += samp_lerp(B);   // waits B only; A's 8 loads in flight
        samp_issue(volb, fk0 + (float)(k + 1), sx, sy, sz, p0x, p0y, p0z, B);
        __builtin_amdgcn_sched_barrier(0);   // B(next) cannot sink below
    }
    acc += samp_lerp(A);
    acc += samp_lerp(B);

    // ---- reduce the 4 K-quarters per pixel through LDS ----
    __shared__ float part[256];
    part[tid] = acc;
    __syncthreads();
    if (kq == 0) {
        const float s = part[wl] + part[wl + 64] + part[wl + 128] + part[wl + 192];
        out[(((b * 256) + h) << 8) + w] = s;
    }
}

extern "C" void kernel_launch(void* const* d_in, const int* in_sizes, int n_in,
                              void* d_out, int out_size, void* d_ws, size_t ws_size,
                              hipStream_t stream) {
    const float* x      = (const float*)d_in[0];  // [2,1,256,256,256]
    const float* Tm     = (const float*)d_in[2];  // [2,3,4]
    const float* corner = (const float*)d_in[3];  // [2,8,4]
    const float* param  = (const float*)d_in[4];  // [4]
    float* out = (float*)d_out;                   // [2,1,256,256]

    const int blocks = 2 * 256 * (256 / 64);      // 2048
    prost_fwd<<<blocks, 256, 0, stream>>>(x, Tm, corner, param, out);
}

// Round 11
// 234.402 us; speedup vs baseline: 1.1886x; 1.1806x over previous
//
#include <hip/hip_runtime.h>

// ProST projective spatial transformer forward:
// out[b,0,h,w] = sum_k trilinear(vol[b], M_b * (s + t_k * dir(h,w)))
// B=2, C=1, vol 256^3, detector 256x256, K=128.
//
// R2:  VGPR=20, VALUBusy=21%, 133us -> latency theory.
// R10: pinned 2-deep pipeline, VGPR=32 (codegen changed) -> 132us. NEUTRAL.
//      => memory pipe is gather-instruction-throughput bound (~39 cy/gather
//      per CU), not latency bound. Lever = fewer gather instructions.
// R11: x-pair float2 loads: 4 gathers/sample instead of 8. Border semantics
//      via bx=clamp(floor,0,254), xe=clamp(fx-bx,0,1) (matches reference
//      clip: degenerate lerp at both edges). aligned(4) keeps it correct
//      even if the backend splits the load.

#define VOL_N      256
#define K_SAMP     128
#define K_SPLIT    4
#define K_PER      (K_SAMP / K_SPLIT)   // 32

typedef float v2f __attribute__((ext_vector_type(2), aligned(4)));

struct Samp {
    v2f p00, p01, p10, p11;   // [x0,x0+1] pairs for the 4 (y,z) rows
    float xe, yd, zd;
};

__device__ __forceinline__ void samp_issue(
    const float* __restrict__ volb, float fk,
    float sx, float sy, float sz,
    float p0x, float p0y, float p0z, Samp& S)
{
    const float fx = fmaf(fk, sx, p0x);
    const float fy = fmaf(fk, sy, p0y);
    const float fz = fmaf(fk, sz, p0z);
    const float x0f = floorf(fx), y0f = floorf(fy), z0f = floorf(fz);
    S.yd = fy - y0f;
    S.zd = fz - z0f;
    int bx = (int)x0f;
    bx = min(max(bx, 0), 254);
    // xe: in-range -> fractional xd; floor<0 -> 0 (both=vol[0]);
    // floor>=255 -> 1 (both=vol[255]). Matches reference clip semantics.
    S.xe = fminf(fmaxf(fx - (float)bx, 0.0f), 1.0f);
    int iy0 = (int)y0f, iz0 = (int)z0f;
    int iy1 = iy0 + 1,  iz1 = iz0 + 1;
    iy0 = min(max(iy0, 0), 255); iy1 = min(max(iy1, 0), 255);
    iz0 = min(max(iz0, 0), 255); iz1 = min(max(iz1, 0), 255);
    const int a00 = (iz0 << 16) + (iy0 << 8) + bx;
    const int a01 = (iz0 << 16) + (iy1 << 8) + bx;
    const int a10 = (iz1 << 16) + (iy0 << 8) + bx;
    const int a11 = (iz1 << 16) + (iy1 << 8) + bx;
    S.p00 = *(const v2f*)(volb + a00);
    S.p01 = *(const v2f*)(volb + a01);
    S.p10 = *(const v2f*)(volb + a10);
    S.p11 = *(const v2f*)(volb + a11);
}

__device__ __forceinline__ float samp_lerp(const Samp& S)
{
    const float c00 = fmaf(S.xe, S.p00.y - S.p00.x, S.p00.x);
    const float c01 = fmaf(S.xe, S.p01.y - S.p01.x, S.p01.x);
    const float c10 = fmaf(S.xe, S.p10.y - S.p10.x, S.p10.x);
    const float c11 = fmaf(S.xe, S.p11.y - S.p11.x, S.p11.x);
    const float c0  = fmaf(S.yd, c01 - c00, c00);
    const float c1  = fmaf(S.yd, c11 - c10, c10);
    return fmaf(S.zd, c1 - c0, c0);
}

__global__ __launch_bounds__(256) void prost_fwd(
    const float* __restrict__ vol,     // [B,1,256,256,256]
    const float* __restrict__ Tm,      // [B,3,4]
    const float* __restrict__ corner,  // [B,8,4]
    const float* __restrict__ param,   // [src, det, pix_spacing, step_size]
    float* __restrict__ out)           // [B,1,256,256]
{
    const int tid  = threadIdx.x;
    const int wl   = tid & 63;          // lane within w-group
    const int kq   = tid >> 6;          // which K-quarter
    const int bid  = blockIdx.x;
    const int wblk = bid & 3;           // W/64 = 4 groups
    const int h    = (bid >> 2) & 255;
    const int b    = bid >> 10;         // batch

    const float src = param[0];
    const float det = param[1];
    const float pix = param[2];

    // ---- transform matrix (uniform per block -> scalar loads) ----
    const float* M = Tm + b * 12;
    const float m00 = M[0], m01 = M[1],  m02 = M[2],  m03 = M[3];
    const float m10 = M[4], m11 = M[5],  m12 = M[6],  m13 = M[7];
    const float m20 = M[8], m21 = M[9],  m22 = M[10], m23 = M[11];

    // ---- ray-distance range from the 8 transformed corners ----
    const float* cp = corner + b * 32;
    float dmin =  1e30f, dmax = -1e30f;
    #pragma unroll
    for (int c = 0; c < 8; ++c) {
        const float cx = cp[c * 4 + 0], cy = cp[c * 4 + 1];
        const float cz = cp[c * 4 + 2], cw = cp[c * 4 + 3];
        const float q0 = m00 * cx + m01 * cy + m02 * cz + m03 * cw;
        const float q1 = m10 * cx + m11 * cy + m12 * cz + m13 * cw;
        const float q2 = m20 * cx + m21 * cy + m22 * cz + m23 * cw - src;
        const float d  = sqrtf(q0 * q0 + q1 * q1 + q2 * q2);
        dmin = fminf(dmin, d);
        dmax = fmaxf(dmax, d);
    }

    // ---- per-pixel ray direction (normalized) ----
    const int   w  = wblk * 64 + wl;
    const float wx = ((float)w - 127.5f) * pix;
    const float hy = ((float)h - 127.5f) * pix;
    const float inv_n = 1.0f / sqrtf(wx * wx + hy * hy + det * det);
    const float dirx = wx * inv_n;
    const float diry = hy * inv_n;
    const float dirz = -det * inv_n;

    // ---- fold affine chain: voxel_coord_i(t) = ca_i + t * cb_i ----
    const float bd0 = m00 * dirx + m01 * diry + m02 * dirz;
    const float bd1 = m10 * dirx + m11 * diry + m12 * dirz;
    const float bd2 = m20 * dirx + m21 * diry + m22 * dirz;
    const float a0  = m02 * src + m03;
    const float a1  = m12 * src + m13;
    const float a2  = m22 * src + m23;
    const float ca0 = (a0 + 1.0f) * 127.5f, cb0 = bd0 * 127.5f;
    const float ca1 = (a1 + 1.0f) * 127.5f, cb1 = bd1 * 127.5f;
    const float ca2 = (a2 + 1.0f) * 127.5f, cb2 = bd2 * 127.5f;

    // t_k = dmin + dspan * k/(K-1)  ->  voxel(k) = p0 + k * s
    const float dspan = dmax - dmin;
    const float tstep = dspan * (1.0f / (float)(K_SAMP - 1));
    const float p0x = fmaf(dmin, cb0, ca0), sx = tstep * cb0;
    const float p0y = fmaf(dmin, cb1, ca1), sy = tstep * cb1;
    const float p0z = fmaf(dmin, cb2, ca2), sz = tstep * cb2;

    const float* __restrict__ volb =
        vol + (size_t)b * (VOL_N * VOL_N * VOL_N);

    // ---- K-march, 2-deep software pipeline, scheduler-pinned ----
    float acc = 0.0f;
    const float fk0 = (float)(kq * K_PER);
    Samp A, B;
    samp_issue(volb, fk0 + 0.0f, sx, sy, sz, p0x, p0y, p0z, A);
    samp_issue(volb, fk0 + 1.0f, sx, sy, sz, p0x, p0y, p0z, B);
    __builtin_amdgcn_sched_barrier(0);   // loads above stay above
    #pragma unroll 3
    for (int k = 2; k < K_PER; k += 2) {
        acc += samp_lerp(A);   // waits A only; B's loads in flight
        samp_issue(volb, fk0 + (float)k, sx, sy, sz, p0x, p0y, p0z, A);
        __builtin_amdgcn_sched_barrier(0);   // A(next) cannot sink below
        acc += samp_lerp(B);   // waits B only; A's loads in flight
        samp_issue(volb, fk0 + (float)(k + 1), sx, sy, sz, p0x, p0y, p0z, B);
        __builtin_amdgcn_sched_barrier(0);   // B(next) cannot sink below
    }
    acc += samp_lerp(A);
    acc += samp_lerp(B);

    // ---- reduce the 4 K-quarters per pixel through LDS ----
    __shared__ float part[256];
    part[tid] = acc;
    __syncthreads();
    if (kq == 0) {
        const float s = part[wl] + part[wl + 64] + part[wl + 128] + part[wl + 192];
        out[(((b * 256) + h) << 8) + w] = s;
    }
}

extern "C" void kernel_launch(void* const* d_in, const int* in_sizes, int n_in,
                              void* d_out, int out_size, void* d_ws, size_t ws_size,
                              hipStream_t stream) {
    const float* x      = (const float*)d_in[0];  // [2,1,256,256,256]
    const float* Tm     = (const float*)d_in[2];  // [2,3,4]
    const float* corner = (const float*)d_in[3];  // [2,8,4]
    const float* param  = (const float*)d_in[4];  // [4]
    float* out = (float*)d_out;                   // [2,1,256,256]

    const int blocks = 2 * 256 * (256 / 64);      // 2048
    prost_fwd<<<blocks, 256, 0, stream>>>(x, Tm, corner, param, out);
}